// Round 1
// baseline (426.784 us; speedup 1.0000x reference)
//
#include <hip/hip_runtime.h>

#define NN 50000
#define NE 800000
#define HD 128

typedef __attribute__((ext_vector_type(8))) short s16x8;
typedef __attribute__((ext_vector_type(4))) float f32x4;

static __device__ __forceinline__ unsigned short f2bf(float f) {
    unsigned int u = __float_as_uint(f);
    u = (u + 0x7FFFu + ((u >> 16) & 1u)) >> 16;
    return (unsigned short)u;
}
static __device__ __forceinline__ float bf2f(unsigned short h) {
    return __uint_as_float(((unsigned int)h) << 16);
}

// ---------------------------------------------------------------------------
// prep: Wpc = pw2 @ mw1[256:288,:]  (32x128), b_c = pb2 @ mw1[256:288,:] + mb1
// also detect whether edge_index arrived as int64 (viewed as int32 pairs)
// ---------------------------------------------------------------------------
__global__ void prep_kernel(const float* __restrict__ pw2, const float* __restrict__ pb2,
                            const float* __restrict__ mw1, const float* __restrict__ mb1,
                            const int* __restrict__ ei,
                            float* __restrict__ Wpc, float* __restrict__ bc,
                            int* __restrict__ flag)
{
    int tid = threadIdx.x;
    for (int idx = tid; idx < 32 * 128; idx += 256) {
        int j = idx >> 7, k = idx & 127;
        float s = 0.f;
        #pragma unroll 8
        for (int i = 0; i < 32; ++i) s += pw2[j * 32 + i] * mw1[(256 + i) * 128 + k];
        Wpc[idx] = s;
    }
    if (tid < 128) {
        float s = mb1[tid];
        #pragma unroll 8
        for (int i = 0; i < 32; ++i) s += pb2[i] * mw1[(256 + i) * 128 + tid];
        bc[tid] = s;
    }
    if (tid == 0) {
        // int64 edge data viewed as int32: odd words are all zero (values < 2^31)
        int z = 1;
        for (int k = 0; k < 16; ++k) if (ei[2 * k + 1] != 0) z = 0;
        *flag = z;
    }
}

// ---------------------------------------------------------------------------
// stage 1: xa = bf16(x @ mw1[0:128,:]), xb = bf16(x @ mw1[128:256,:])
// ---------------------------------------------------------------------------
__global__ __launch_bounds__(256, 2) void node_pre_kernel(
    const float* __restrict__ x, const float* __restrict__ mw1,
    unsigned short* __restrict__ xa, unsigned short* __restrict__ xb)
{
    __shared__ __align__(16) unsigned short sB[256 * 136]; // [c][k] col-major, pad 136

    int tid = threadIdx.x;
    for (int idx = tid; idx < 256 * 128; idx += 256) {
        int c = idx & 255, k = idx >> 8;
        float v = (c < 128) ? mw1[k * 128 + c] : mw1[(128 + k) * 128 + (c - 128)];
        sB[c * 136 + k] = f2bf(v);
    }
    __syncthreads();

    int lane = tid & 63, wv = tid >> 6;
    int r16 = lane & 15, g4 = lane >> 4;
    int ntile = (NN + 63) >> 6; // 782

    for (int t = blockIdx.x; t < ntile; t += gridDim.x) {
        int r0 = t * 64 + wv * 16;
        int row = r0 + r16;
        int rowc = row < NN ? row : NN - 1;
        s16x8 a[4];
        #pragma unroll
        for (int ks = 0; ks < 4; ++ks) {
            const float* p = &x[rowc * HD + ks * 32 + g4 * 8];
            float4 v0 = *(const float4*)p;
            float4 v1 = *(const float4*)(p + 4);
            s16x8 av;
            av[0] = f2bf(v0.x); av[1] = f2bf(v0.y); av[2] = f2bf(v0.z); av[3] = f2bf(v0.w);
            av[4] = f2bf(v1.x); av[5] = f2bf(v1.y); av[6] = f2bf(v1.z); av[7] = f2bf(v1.w);
            a[ks] = av;
        }
        #pragma unroll
        for (int tc = 0; tc < 16; ++tc) {
            f32x4 acc = {0.f, 0.f, 0.f, 0.f};
            #pragma unroll
            for (int ks = 0; ks < 4; ++ks) {
                s16x8 b = *(const s16x8*)&sB[(tc * 16 + r16) * 136 + ks * 32 + g4 * 8];
                acc = __builtin_amdgcn_mfma_f32_16x16x32_bf16(a[ks], b, acc, 0, 0, 0);
            }
            #pragma unroll
            for (int j = 0; j < 4; ++j) {
                int r = r0 + g4 * 4 + j;
                if (r < NN) {
                    int c = tc * 16 + r16;
                    if (c < 128) xa[r * HD + c] = f2bf(acc[j]);
                    else         xb[r * HD + (c - 128)] = f2bf(acc[j]);
                }
            }
        }
    }
}

// ---------------------------------------------------------------------------
// stage 2 (edges): pf = relu(dp@pw1+pb1); h1 = pf@Wpc + xa[row] + xb[col] + b_c
// msg = relu(h1)@mw2 + mb2 ; atomic scatter-add into agg[col]
// ---------------------------------------------------------------------------
__global__ __launch_bounds__(256, 2) void edge_kernel(
    const float* __restrict__ pos, const int* __restrict__ ei,
    const float* __restrict__ pw1, const float* __restrict__ pb1,
    const float* __restrict__ mw2, const float* __restrict__ mb2,
    const unsigned short* __restrict__ xa, const unsigned short* __restrict__ xb,
    const float* __restrict__ Wpc, const float* __restrict__ bc,
    const int* __restrict__ flag, float* __restrict__ agg)
{
    __shared__ __align__(16) unsigned short sB[128 * 136];  // mw2 [c][k]
    __shared__ __align__(16) unsigned short sW[128 * 40];   // Wpc [c][k<32]
    __shared__ __align__(16) unsigned short sPF[64 * 40];   // pf tile [e][k<32]
    __shared__ __align__(16) unsigned short sHR[64 * 136];  // relu(h1) [e][k]
    __shared__ int sER[64], sEC[64];
    __shared__ float sDP[64 * 3];
    __shared__ float sbc[128], smb2[128], spw1[96], spb1[32];

    int tid = threadIdx.x;
    for (int idx = tid; idx < 128 * 128; idx += 256) {
        int c = idx & 127, k = idx >> 7;
        sB[c * 136 + k] = f2bf(mw2[k * 128 + c]);
    }
    for (int idx = tid; idx < 32 * 128; idx += 256) {
        int c = idx & 127, k = idx >> 7;
        sW[c * 40 + k] = f2bf(Wpc[k * 128 + c]);
    }
    if (tid < 128) { sbc[tid] = bc[tid]; smb2[tid] = mb2[tid]; }
    if (tid < 96) spw1[tid] = pw1[tid];
    if (tid < 32) spb1[tid] = pb1[tid];
    int idx64 = flag[0];
    __syncthreads();

    int lane = tid & 63, wv = tid >> 6;
    int r16 = lane & 15, g4 = lane >> 4;
    int ntile = NE / 64; // 12500 exactly

    for (int t = blockIdx.x; t < ntile; t += gridDim.x) {
        int e0 = t * 64;
        if (tid < 64) {
            int e = e0 + tid;
            int r, c;
            if (idx64) { r = ei[2 * e]; c = ei[2 * NE + 2 * e]; }
            else       { r = ei[e];     c = ei[NE + e]; }
            sER[tid] = r; sEC[tid] = c;
            #pragma unroll
            for (int d = 0; d < 3; ++d) sDP[tid * 3 + d] = pos[r * 3 + d] - pos[c * 3 + d];
        }
        __syncthreads();
        {
            int e = tid >> 2, i0 = (tid & 3) * 8;
            float d0 = sDP[e * 3], d1 = sDP[e * 3 + 1], d2 = sDP[e * 3 + 2];
            #pragma unroll
            for (int i = 0; i < 8; ++i) {
                int ii = i0 + i;
                float v = fmaf(d0, spw1[ii], fmaf(d1, spw1[32 + ii], fmaf(d2, spw1[64 + ii], spb1[ii])));
                sPF[e * 40 + ii] = f2bf(fmaxf(v, 0.f));
            }
        }
        __syncthreads();

        // GEMM1: h1[64][128] = PF @ Wpc (+gathers), each wave owns 16 edge-rows
        s16x8 apf = *(const s16x8*)&sPF[(wv * 16 + r16) * 40 + g4 * 8];
        #pragma unroll
        for (int tc = 0; tc < 8; ++tc) {
            int col = tc * 16 + r16;
            s16x8 b = *(const s16x8*)&sW[col * 40 + g4 * 8];
            f32x4 acc = {0.f, 0.f, 0.f, 0.f};
            acc = __builtin_amdgcn_mfma_f32_16x16x32_bf16(apf, b, acc, 0, 0, 0);
            float bcv = sbc[col];
            #pragma unroll
            for (int j = 0; j < 4; ++j) {
                int e = wv * 16 + g4 * 4 + j;
                float v = acc[j] + bcv + bf2f(xa[sER[e] * HD + col]) + bf2f(xb[sEC[e] * HD + col]);
                sHR[e * 136 + col] = f2bf(fmaxf(v, 0.f));
            }
        }
        // wave reads back only its own 16 rows -> no cross-wave barrier needed

        // GEMM2: msg = HR @ mw2 + mb2, scatter
        s16x8 a2[4];
        #pragma unroll
        for (int ks = 0; ks < 4; ++ks)
            a2[ks] = *(const s16x8*)&sHR[(wv * 16 + r16) * 136 + ks * 32 + g4 * 8];
        #pragma unroll
        for (int tc = 0; tc < 8; ++tc) {
            int col = tc * 16 + r16;
            float mbv = smb2[col];
            f32x4 acc = {mbv, mbv, mbv, mbv};
            #pragma unroll
            for (int ks = 0; ks < 4; ++ks) {
                s16x8 b = *(const s16x8*)&sB[col * 136 + ks * 32 + g4 * 8];
                acc = __builtin_amdgcn_mfma_f32_16x16x32_bf16(a2[ks], b, acc, 0, 0, 0);
            }
            #pragma unroll
            for (int j = 0; j < 4; ++j) {
                int e = wv * 16 + g4 * 4 + j;
                unsafeAtomicAdd(&agg[sEC[e] * HD + col], acc[j]);
            }
        }
        __syncthreads(); // protect sER/sEC/sDP/sPF before next tile restages
    }
}

// ---------------------------------------------------------------------------
// stage 3: out = relu(x@uw1_a + agg@uw1_b + ub1) @ uw2 + ub2
// ---------------------------------------------------------------------------
__global__ __launch_bounds__(256, 1) void update_kernel(
    const float* __restrict__ x, const float* __restrict__ agg,
    const float* __restrict__ uw1, const float* __restrict__ ub1,
    const float* __restrict__ uw2, const float* __restrict__ ub2,
    float* __restrict__ out)
{
    __shared__ __align__(16) unsigned short sB1[128 * 264]; // uw1 [c][k<256]
    __shared__ __align__(16) unsigned short sB2[128 * 136]; // uw2 [c][k<128]
    __shared__ __align__(16) unsigned short sHR[64 * 136];
    __shared__ float sub1[128], sub2[128];

    int tid = threadIdx.x;
    for (int idx = tid; idx < 256 * 128; idx += 256) {
        int c = idx & 127, k = idx >> 7;
        sB1[c * 264 + k] = f2bf(uw1[k * 128 + c]);
    }
    for (int idx = tid; idx < 128 * 128; idx += 256) {
        int c = idx & 127, k = idx >> 7;
        sB2[c * 136 + k] = f2bf(uw2[k * 128 + c]);
    }
    if (tid < 128) { sub1[tid] = ub1[tid]; sub2[tid] = ub2[tid]; }
    __syncthreads();

    int lane = tid & 63, wv = tid >> 6;
    int r16 = lane & 15, g4 = lane >> 4;
    int ntile = (NN + 63) >> 6;

    for (int t = blockIdx.x; t < ntile; t += gridDim.x) {
        int r0 = t * 64 + wv * 16;
        int row = r0 + r16;
        int rowc = row < NN ? row : NN - 1;
        s16x8 a[8];
        #pragma unroll
        for (int ks = 0; ks < 8; ++ks) {
            int k = ks * 32 + g4 * 8;
            const float* p = (k < 128) ? &x[rowc * HD + k] : &agg[rowc * HD + (k - 128)];
            float4 v0 = *(const float4*)p;
            float4 v1 = *(const float4*)(p + 4);
            s16x8 av;
            av[0] = f2bf(v0.x); av[1] = f2bf(v0.y); av[2] = f2bf(v0.z); av[3] = f2bf(v0.w);
            av[4] = f2bf(v1.x); av[5] = f2bf(v1.y); av[6] = f2bf(v1.z); av[7] = f2bf(v1.w);
            a[ks] = av;
        }
        #pragma unroll
        for (int tc = 0; tc < 8; ++tc) {
            int col = tc * 16 + r16;
            float bv = sub1[col];
            f32x4 acc = {bv, bv, bv, bv};
            #pragma unroll
            for (int ks = 0; ks < 8; ++ks) {
                s16x8 b = *(const s16x8*)&sB1[col * 264 + ks * 32 + g4 * 8];
                acc = __builtin_amdgcn_mfma_f32_16x16x32_bf16(a[ks], b, acc, 0, 0, 0);
            }
            #pragma unroll
            for (int j = 0; j < 4; ++j) {
                int e = wv * 16 + g4 * 4 + j;
                sHR[e * 136 + col] = f2bf(fmaxf(acc[j], 0.f));
            }
        }
        s16x8 a2[4];
        #pragma unroll
        for (int ks = 0; ks < 4; ++ks)
            a2[ks] = *(const s16x8*)&sHR[(wv * 16 + r16) * 136 + ks * 32 + g4 * 8];
        #pragma unroll
        for (int tc = 0; tc < 8; ++tc) {
            int col = tc * 16 + r16;
            float bv = sub2[col];
            f32x4 acc = {bv, bv, bv, bv};
            #pragma unroll
            for (int ks = 0; ks < 4; ++ks) {
                s16x8 b = *(const s16x8*)&sB2[col * 136 + ks * 32 + g4 * 8];
                acc = __builtin_amdgcn_mfma_f32_16x16x32_bf16(a2[ks], b, acc, 0, 0, 0);
            }
            #pragma unroll
            for (int j = 0; j < 4; ++j) {
                int r = r0 + g4 * 4 + j;
                if (r < NN) out[r * HD + col] = acc[j];
            }
        }
        __syncthreads(); // sHR rows are wave-private, but keep tiles cleanly separated
    }
}

// ---------------------------------------------------------------------------
extern "C" void kernel_launch(void* const* d_in, const int* in_sizes, int n_in,
                              void* d_out, int out_size, void* d_ws, size_t ws_size,
                              hipStream_t stream)
{
    const float* x   = (const float*)d_in[0];
    const float* pos = (const float*)d_in[1];
    const int*   ei  = (const int*)d_in[2];
    const float* pw1 = (const float*)d_in[3];
    const float* pb1 = (const float*)d_in[4];
    const float* pw2 = (const float*)d_in[5];
    const float* pb2 = (const float*)d_in[6];
    const float* mw1 = (const float*)d_in[7];
    const float* mb1 = (const float*)d_in[8];
    const float* mw2 = (const float*)d_in[9];
    const float* mb2 = (const float*)d_in[10];
    const float* uw1 = (const float*)d_in[11];
    const float* ub1 = (const float*)d_in[12];
    const float* uw2 = (const float*)d_in[13];
    const float* ub2 = (const float*)d_in[14];
    float* out = (float*)d_out;

    char* ws = (char*)d_ws;
    float*          agg  = (float*)(ws);                       // 25,600,000 B
    unsigned short* xa   = (unsigned short*)(ws + 25600000);   // 12,800,000 B
    unsigned short* xb   = (unsigned short*)(ws + 38400000);   // 12,800,000 B
    float*          Wpc  = (float*)(ws + 51200000);            // 16,384 B
    float*          bcv  = (float*)(ws + 51216384);            // 512 B
    int*            flag = (int*)(ws + 51216896);

    hipMemsetAsync(agg, 0, (size_t)NN * HD * sizeof(float), stream);
    prep_kernel<<<1, 256, 0, stream>>>(pw2, pb2, mw1, mb1, ei, Wpc, bcv, flag);
    node_pre_kernel<<<512, 256, 0, stream>>>(x, mw1, xa, xb);
    edge_kernel<<<512, 256, 0, stream>>>(pos, ei, pw1, pb1, mw2, mb2, xa, xb, Wpc, bcv, flag, agg);
    update_kernel<<<256, 256, 0, stream>>>(x, agg, uw1, ub1, uw2, ub2, out);
}

// Round 2
// 375.625 us; speedup vs baseline: 1.1362x; 1.1362x over previous
//
#include <hip/hip_runtime.h>

#define NN 50000
#define NE 800000
#define HD 128
#define NTILE (NE / 32)      // 25000
#define SCAN_CHUNK 1024
#define SCAN_BLOCKS ((NN + SCAN_CHUNK - 1) / SCAN_CHUNK)  // 49

typedef __attribute__((ext_vector_type(8))) short s16x8;
typedef __attribute__((ext_vector_type(4))) float f32x4;

static __device__ __forceinline__ unsigned short f2bf(float f) {
    unsigned int u = __float_as_uint(f);
    u = (u + 0x7FFFu + ((u >> 16) & 1u)) >> 16;
    return (unsigned short)u;
}
static __device__ __forceinline__ float bf2f(unsigned short h) {
    return __uint_as_float(((unsigned int)h) << 16);
}

// ---------------------------------------------------------------------------
// prep: Wpc = pw2 @ mw1[256:288,:]  (32x128), b_c = pb2 @ mw1[256:288,:] + mb1
// also detect whether edge_index arrived as int64 (viewed as int32 pairs)
// ---------------------------------------------------------------------------
__global__ void prep_kernel(const float* __restrict__ pw2, const float* __restrict__ pb2,
                            const float* __restrict__ mw1, const float* __restrict__ mb1,
                            const int* __restrict__ ei,
                            float* __restrict__ Wpc, float* __restrict__ bc,
                            int* __restrict__ flag)
{
    int tid = threadIdx.x;
    for (int idx = tid; idx < 32 * 128; idx += 256) {
        int j = idx >> 7, k = idx & 127;
        float s = 0.f;
        #pragma unroll 8
        for (int i = 0; i < 32; ++i) s += pw2[j * 32 + i] * mw1[(256 + i) * 128 + k];
        Wpc[idx] = s;
    }
    if (tid < 128) {
        float s = mb1[tid];
        #pragma unroll 8
        for (int i = 0; i < 32; ++i) s += pb2[i] * mw1[(256 + i) * 128 + tid];
        bc[tid] = s;
    }
    if (tid == 0) {
        int z = 1;
        for (int k = 0; k < 16; ++k) if (ei[2 * k + 1] != 0) z = 0;
        *flag = z;
    }
}

// ---------------------------------------------------------------------------
// counting sort of edges by destination (col)
// ---------------------------------------------------------------------------
__global__ void hist_kernel(const int* __restrict__ ei, const int* __restrict__ flag,
                            int* __restrict__ cnt)
{
    int e = blockIdx.x * 256 + threadIdx.x;
    if (e >= NE) return;
    int c = flag[0] ? ei[2 * NE + 2 * e] : ei[NE + e];
    atomicAdd(&cnt[c], 1);
}

// per-chunk exclusive scan -> cursor (without carry), chunk totals -> bsum
__global__ void scan1_kernel(const int* __restrict__ cnt, int* __restrict__ cursor,
                             int* __restrict__ bsum)
{
    __shared__ int tot[256];
    int b = blockIdx.x, t = threadIdx.x;
    int i0 = b * SCAN_CHUNK + t * 4;
    int v[4];
    #pragma unroll
    for (int k = 0; k < 4; ++k) v[k] = (i0 + k < NN) ? cnt[i0 + k] : 0;
    tot[t] = v[0] + v[1] + v[2] + v[3];
    __syncthreads();
    if (t == 0) {
        int run = 0;
        for (int i = 0; i < 256; ++i) { int x = tot[i]; tot[i] = run; run += x; }
        bsum[b] = run;
    }
    __syncthreads();
    int p = tot[t];
    #pragma unroll
    for (int k = 0; k < 4; ++k) {
        if (i0 + k < NN) cursor[i0 + k] = p;
        p += v[k];
    }
}

__global__ void scan2_kernel(int* __restrict__ bsum)
{
    if (threadIdx.x == 0) {
        int run = 0;
        for (int i = 0; i < SCAN_BLOCKS; ++i) { int x = bsum[i]; bsum[i] = run; run += x; }
    }
}

__global__ void scan3_kernel(int* __restrict__ cursor, const int* __restrict__ bsum)
{
    int b = blockIdx.x, t = threadIdx.x;
    int carry = bsum[b];
    int i0 = b * SCAN_CHUNK + t * 4;
    #pragma unroll
    for (int k = 0; k < 4; ++k)
        if (i0 + k < NN) cursor[i0 + k] += carry;
}

__global__ void scatter_kernel(const int* __restrict__ ei, const int* __restrict__ flag,
                               int* __restrict__ cursor, int2* __restrict__ sRC)
{
    int e = blockIdx.x * 256 + threadIdx.x;
    if (e >= NE) return;
    int r, c;
    if (flag[0]) { r = ei[2 * e]; c = ei[2 * NE + 2 * e]; }
    else         { r = ei[e];     c = ei[NE + e]; }
    int p = atomicAdd(&cursor[c], 1);
    sRC[p] = make_int2(r, c);
}

// ---------------------------------------------------------------------------
// stage 1: xa = bf16(x @ mw1[0:128,:]), xb = bf16(x @ mw1[128:256,:])
// ---------------------------------------------------------------------------
__global__ __launch_bounds__(256, 2) void node_pre_kernel(
    const float* __restrict__ x, const float* __restrict__ mw1,
    unsigned short* __restrict__ xa, unsigned short* __restrict__ xb)
{
    __shared__ __align__(16) unsigned short sB[256 * 136]; // [c][k] col-major, pad 136

    int tid = threadIdx.x;
    for (int idx = tid; idx < 256 * 128; idx += 256) {
        int c = idx & 255, k = idx >> 8;
        float v = (c < 128) ? mw1[k * 128 + c] : mw1[(128 + k) * 128 + (c - 128)];
        sB[c * 136 + k] = f2bf(v);
    }
    __syncthreads();

    int lane = tid & 63, wv = tid >> 6;
    int r16 = lane & 15, g4 = lane >> 4;
    int ntile = (NN + 63) >> 6; // 782

    for (int t = blockIdx.x; t < ntile; t += gridDim.x) {
        int r0 = t * 64 + wv * 16;
        int row = r0 + r16;
        int rowc = row < NN ? row : NN - 1;
        s16x8 a[4];
        #pragma unroll
        for (int ks = 0; ks < 4; ++ks) {
            const float* p = &x[rowc * HD + ks * 32 + g4 * 8];
            float4 v0 = *(const float4*)p;
            float4 v1 = *(const float4*)(p + 4);
            s16x8 av;
            av[0] = f2bf(v0.x); av[1] = f2bf(v0.y); av[2] = f2bf(v0.z); av[3] = f2bf(v0.w);
            av[4] = f2bf(v1.x); av[5] = f2bf(v1.y); av[6] = f2bf(v1.z); av[7] = f2bf(v1.w);
            a[ks] = av;
        }
        #pragma unroll
        for (int tc = 0; tc < 16; ++tc) {
            f32x4 acc = {0.f, 0.f, 0.f, 0.f};
            #pragma unroll
            for (int ks = 0; ks < 4; ++ks) {
                s16x8 b = *(const s16x8*)&sB[(tc * 16 + r16) * 136 + ks * 32 + g4 * 8];
                acc = __builtin_amdgcn_mfma_f32_16x16x32_bf16(a[ks], b, acc, 0, 0, 0);
            }
            #pragma unroll
            for (int j = 0; j < 4; ++j) {
                int r = r0 + g4 * 4 + j;
                if (r < NN) {
                    int c = tc * 16 + r16;
                    if (c < 128) xa[r * HD + c] = f2bf(acc[j]);
                    else         xb[r * HD + (c - 128)] = f2bf(acc[j]);
                }
            }
        }
    }
}

// ---------------------------------------------------------------------------
// stage 2 (edges, SORTED by col): per 32-edge tile:
//   pf = relu(dp@pw1+pb1)
//   sH1 = xa[row] + xb[col] + b_c  (cooperative 16B vector gathers)
//   h1 = pf@Wpc + sH1 ; HR = relu(h1)
//   msg = HR @ mw2 + mb2 -> sMSG (LDS)
//   segmented reduce over sorted cols -> few atomics into agg
// ---------------------------------------------------------------------------
__global__ __launch_bounds__(256, 2) void edge_kernel(
    const float* __restrict__ pos, const int2* __restrict__ sRC,
    const float* __restrict__ pw1, const float* __restrict__ pb1,
    const float* __restrict__ mw2, const float* __restrict__ mb2,
    const unsigned short* __restrict__ xa, const unsigned short* __restrict__ xb,
    const float* __restrict__ Wpc, const float* __restrict__ bc,
    float* __restrict__ agg)
{
    __shared__ __align__(16) unsigned short sB[128 * 136];  // mw2 [c][k]
    __shared__ __align__(16) unsigned short sW[128 * 40];   // Wpc [c][k<32]
    __shared__ __align__(16) unsigned short sPF[32 * 40];   // pf tile [e][k<32]
    __shared__ __align__(16) unsigned short sHR[32 * 136];  // relu(h1) [e][k]
    __shared__ __align__(16) float sACC[32 * 132];          // phase1: xa+xb+bc ; phase2: msg
    __shared__ int sER[32], sEC[32];
    __shared__ float sDPl[32 * 3];
    __shared__ float sbc[128], smb2[128], spw1[96], spb1[32];

    int tid = threadIdx.x;
    for (int idx = tid; idx < 128 * 128; idx += 256) {
        int c = idx & 127, k = idx >> 7;
        sB[c * 136 + k] = f2bf(mw2[k * 128 + c]);
    }
    for (int idx = tid; idx < 32 * 128; idx += 256) {
        int c = idx & 127, k = idx >> 7;
        sW[c * 40 + k] = f2bf(Wpc[k * 128 + c]);
    }
    if (tid < 128) { sbc[tid] = bc[tid]; smb2[tid] = mb2[tid]; }
    if (tid < 96) spw1[tid] = pw1[tid];
    if (tid < 32) spb1[tid] = pb1[tid];
    __syncthreads();

    int lane = tid & 63, wv = tid >> 6;
    int r16 = lane & 15, g4 = lane >> 4;
    int rt = wv & 1;           // row(edge)-tile of this wave
    int cq = wv >> 1;          // col-quarter base

    for (int t = blockIdx.x; t < NTILE; t += gridDim.x) {
        int e0 = t * 32;
        // ---- phase A: edge meta
        if (tid < 32) {
            int2 rc = sRC[e0 + tid];
            sER[tid] = rc.x; sEC[tid] = rc.y;
            #pragma unroll
            for (int d = 0; d < 3; ++d)
                sDPl[tid * 3 + d] = pos[rc.x * 3 + d] - pos[rc.y * 3 + d];
        }
        __syncthreads();
        // ---- phase B: pos-MLP layer1 + gather staging
        {
            int e = tid >> 3, i0 = (tid & 7) * 4;
            float d0 = sDPl[e * 3], d1 = sDPl[e * 3 + 1], d2 = sDPl[e * 3 + 2];
            #pragma unroll
            for (int i = 0; i < 4; ++i) {
                int ii = i0 + i;
                float v = fmaf(d0, spw1[ii], fmaf(d1, spw1[32 + ii], fmaf(d2, spw1[64 + ii], spb1[ii])));
                sPF[e * 40 + ii] = f2bf(fmaxf(v, 0.f));
            }
        }
        #pragma unroll
        for (int p = 0; p < 2; ++p) {
            int idx = tid + p * 256;        // 512 slots: 32 edges x 16 chunks(8 bf16)
            int e = idx >> 4, k0 = (idx & 15) * 8;
            s16x8 va = *(const s16x8*)&xa[(size_t)sER[e] * HD + k0];
            s16x8 vb = *(const s16x8*)&xb[(size_t)sEC[e] * HD + k0];
            #pragma unroll
            for (int i = 0; i < 8; ++i)
                sACC[e * 132 + k0 + i] = bf2f((unsigned short)va[i]) + bf2f((unsigned short)vb[i]) + sbc[k0 + i];
        }
        __syncthreads();
        // ---- GEMM1: h1 = PF @ Wpc + sACC ; HR = relu -> sHR
        {
            s16x8 apf = *(const s16x8*)&sPF[(rt * 16 + r16) * 40 + g4 * 8];
            #pragma unroll
            for (int tc4 = 0; tc4 < 4; ++tc4) {
                int col = (cq * 4 + tc4) * 16 + r16;
                s16x8 b = *(const s16x8*)&sW[col * 40 + g4 * 8];
                f32x4 acc = {0.f, 0.f, 0.f, 0.f};
                acc = __builtin_amdgcn_mfma_f32_16x16x32_bf16(apf, b, acc, 0, 0, 0);
                #pragma unroll
                for (int j = 0; j < 4; ++j) {
                    int e = rt * 16 + g4 * 4 + j;
                    float v = acc[j] + sACC[e * 132 + col];
                    sHR[e * 136 + col] = f2bf(fmaxf(v, 0.f));
                }
            }
        }
        __syncthreads();
        // ---- GEMM2: msg = HR @ mw2 + mb2 -> sACC (overlay, sH1 dead)
        {
            s16x8 a2[4];
            #pragma unroll
            for (int ks = 0; ks < 4; ++ks)
                a2[ks] = *(const s16x8*)&sHR[(rt * 16 + r16) * 136 + ks * 32 + g4 * 8];
            #pragma unroll
            for (int tc4 = 0; tc4 < 4; ++tc4) {
                int col = (cq * 4 + tc4) * 16 + r16;
                float mbv = smb2[col];
                f32x4 acc = {mbv, mbv, mbv, mbv};
                #pragma unroll
                for (int ks = 0; ks < 4; ++ks) {
                    s16x8 b = *(const s16x8*)&sB[col * 136 + ks * 32 + g4 * 8];
                    acc = __builtin_amdgcn_mfma_f32_16x16x32_bf16(a2[ks], b, acc, 0, 0, 0);
                }
                #pragma unroll
                for (int j = 0; j < 4; ++j) {
                    int e = rt * 16 + g4 * 4 + j;
                    sACC[e * 132 + col] = acc[j];
                }
            }
        }
        __syncthreads();
        // ---- segmented reduction over sorted cols, few atomics
        {
            int f = tid & 127, h = tid >> 7;
            int be = h * 16;
            int cur = sEC[be];
            float run = sACC[be * 132 + f];
            #pragma unroll 15
            for (int i = 1; i < 16; ++i) {
                int e = be + i;
                int c = sEC[e];
                float v = sACC[e * 132 + f];
                if (c != cur) {
                    unsafeAtomicAdd(&agg[(size_t)cur * HD + f], run);
                    cur = c; run = v;
                } else run += v;
            }
            unsafeAtomicAdd(&agg[(size_t)cur * HD + f], run);
        }
        __syncthreads();
    }
}

// ---------------------------------------------------------------------------
// stage 3: out = relu(x@uw1_a + agg@uw1_b + ub1) @ uw2 + ub2
// ---------------------------------------------------------------------------
__global__ __launch_bounds__(256, 1) void update_kernel(
    const float* __restrict__ x, const float* __restrict__ agg,
    const float* __restrict__ uw1, const float* __restrict__ ub1,
    const float* __restrict__ uw2, const float* __restrict__ ub2,
    float* __restrict__ out)
{
    __shared__ __align__(16) unsigned short sB1[128 * 264]; // uw1 [c][k<256]
    __shared__ __align__(16) unsigned short sB2[128 * 136]; // uw2 [c][k<128]
    __shared__ __align__(16) unsigned short sHR[64 * 136];
    __shared__ float sub1[128], sub2[128];

    int tid = threadIdx.x;
    for (int idx = tid; idx < 256 * 128; idx += 256) {
        int c = idx & 127, k = idx >> 7;
        sB1[c * 264 + k] = f2bf(uw1[k * 128 + c]);
    }
    for (int idx = tid; idx < 128 * 128; idx += 256) {
        int c = idx & 127, k = idx >> 7;
        sB2[c * 136 + k] = f2bf(uw2[k * 128 + c]);
    }
    if (tid < 128) { sub1[tid] = ub1[tid]; sub2[tid] = ub2[tid]; }
    __syncthreads();

    int lane = tid & 63, wv = tid >> 6;
    int r16 = lane & 15, g4 = lane >> 4;
    int ntile = (NN + 63) >> 6;

    for (int t = blockIdx.x; t < ntile; t += gridDim.x) {
        int r0 = t * 64 + wv * 16;
        int row = r0 + r16;
        int rowc = row < NN ? row : NN - 1;
        s16x8 a[8];
        #pragma unroll
        for (int ks = 0; ks < 8; ++ks) {
            int k = ks * 32 + g4 * 8;
            const float* p = (k < 128) ? &x[rowc * HD + k] : &agg[rowc * HD + (k - 128)];
            float4 v0 = *(const float4*)p;
            float4 v1 = *(const float4*)(p + 4);
            s16x8 av;
            av[0] = f2bf(v0.x); av[1] = f2bf(v0.y); av[2] = f2bf(v0.z); av[3] = f2bf(v0.w);
            av[4] = f2bf(v1.x); av[5] = f2bf(v1.y); av[6] = f2bf(v1.z); av[7] = f2bf(v1.w);
            a[ks] = av;
        }
        #pragma unroll
        for (int tc = 0; tc < 8; ++tc) {
            int col = tc * 16 + r16;
            float bv = sub1[col];
            f32x4 acc = {bv, bv, bv, bv};
            #pragma unroll
            for (int ks = 0; ks < 8; ++ks) {
                s16x8 b = *(const s16x8*)&sB1[col * 264 + ks * 32 + g4 * 8];
                acc = __builtin_amdgcn_mfma_f32_16x16x32_bf16(a[ks], b, acc, 0, 0, 0);
            }
            #pragma unroll
            for (int j = 0; j < 4; ++j) {
                int e = wv * 16 + g4 * 4 + j;
                sHR[e * 136 + col] = f2bf(fmaxf(acc[j], 0.f));
            }
        }
        s16x8 a2[4];
        #pragma unroll
        for (int ks = 0; ks < 4; ++ks)
            a2[ks] = *(const s16x8*)&sHR[(wv * 16 + r16) * 136 + ks * 32 + g4 * 8];
        #pragma unroll
        for (int tc = 0; tc < 8; ++tc) {
            int col = tc * 16 + r16;
            float bv = sub2[col];
            f32x4 acc = {bv, bv, bv, bv};
            #pragma unroll
            for (int ks = 0; ks < 4; ++ks) {
                s16x8 b = *(const s16x8*)&sB2[col * 136 + ks * 32 + g4 * 8];
                acc = __builtin_amdgcn_mfma_f32_16x16x32_bf16(a2[ks], b, acc, 0, 0, 0);
            }
            #pragma unroll
            for (int j = 0; j < 4; ++j) {
                int r = r0 + g4 * 4 + j;
                if (r < NN) out[r * HD + col] = acc[j];
            }
        }
        __syncthreads();
    }
}

// ---------------------------------------------------------------------------
extern "C" void kernel_launch(void* const* d_in, const int* in_sizes, int n_in,
                              void* d_out, int out_size, void* d_ws, size_t ws_size,
                              hipStream_t stream)
{
    const float* x   = (const float*)d_in[0];
    const float* pos = (const float*)d_in[1];
    const int*   ei  = (const int*)d_in[2];
    const float* pw1 = (const float*)d_in[3];
    const float* pb1 = (const float*)d_in[4];
    const float* pw2 = (const float*)d_in[5];
    const float* pb2 = (const float*)d_in[6];
    const float* mw1 = (const float*)d_in[7];
    const float* mb1 = (const float*)d_in[8];
    const float* mw2 = (const float*)d_in[9];
    const float* mb2 = (const float*)d_in[10];
    const float* uw1 = (const float*)d_in[11];
    const float* ub1 = (const float*)d_in[12];
    const float* uw2 = (const float*)d_in[13];
    const float* ub2 = (const float*)d_in[14];
    float* out = (float*)d_out;

    char* ws = (char*)d_ws;
    float*          agg    = (float*)(ws);                      // 25,600,000 B
    unsigned short* xa     = (unsigned short*)(ws + 25600000);  // 12,800,000 B
    unsigned short* xb     = (unsigned short*)(ws + 38400000);  // 12,800,000 B
    float*          Wpc    = (float*)(ws + 51200000);           // 16,384 B
    float*          bcv    = (float*)(ws + 51216384);           // 512 B
    int*            flag   = (int*)(ws + 51216896);             // 256 B
    int*            cnt    = (int*)(ws + 51217152);             // 200,704 B
    int*            cursor = (int*)(ws + 51417856);             // 200,704 B
    int*            bsum   = (int*)(ws + 51618560);             // 256 B
    int2*           sRC    = (int2*)(ws + 51618816);            // 6,400,000 B -> end ~58.0 MB

    hipMemsetAsync(agg, 0, (size_t)NN * HD * sizeof(float), stream);
    hipMemsetAsync(cnt, 0, SCAN_BLOCKS * SCAN_CHUNK * sizeof(int), stream);
    prep_kernel<<<1, 256, 0, stream>>>(pw2, pb2, mw1, mb1, ei, Wpc, bcv, flag);
    hist_kernel<<<NE / 256, 256, 0, stream>>>(ei, flag, cnt);
    scan1_kernel<<<SCAN_BLOCKS, 256, 0, stream>>>(cnt, cursor, bsum);
    scan2_kernel<<<1, 64, 0, stream>>>(bsum);
    scan3_kernel<<<SCAN_BLOCKS, 256, 0, stream>>>(cursor, bsum);
    scatter_kernel<<<NE / 256, 256, 0, stream>>>(ei, flag, cursor, sRC);
    node_pre_kernel<<<512, 256, 0, stream>>>(x, mw1, xa, xb);
    edge_kernel<<<512, 256, 0, stream>>>(pos, sRC, pw1, pb1, mw2, mb2, xa, xb, Wpc, bcv, agg);
    update_kernel<<<256, 256, 0, stream>>>(x, agg, uw1, ub1, uw2, ub2, out);
}

// Round 3
// 340.854 us; speedup vs baseline: 1.2521x; 1.1020x over previous
//
#include <hip/hip_runtime.h>

#define NN 50000
#define NE 800000
#define HD 128
#define SCAN_CHUNK 1024
#define SCAN_BLOCKS ((NN + SCAN_CHUNK - 1) / SCAN_CHUNK)  // 49

typedef __attribute__((ext_vector_type(8))) short s16x8;
typedef __attribute__((ext_vector_type(4))) float f32x4;

static __device__ __forceinline__ unsigned short f2bf(float f) {
    unsigned int u = __float_as_uint(f);
    u = (u + 0x7FFFu + ((u >> 16) & 1u)) >> 16;
    return (unsigned short)u;
}
static __device__ __forceinline__ float bf2f(unsigned short h) {
    return __uint_as_float(((unsigned int)h) << 16);
}

// wave-level LDS fence: drain this wave's LDS ops, block compiler reordering.
#define WFENCE() do { asm volatile("s_waitcnt lgkmcnt(0)" ::: "memory"); \
                      __builtin_amdgcn_sched_barrier(0); } while (0)

// ---------------------------------------------------------------------------
// prep: Wpc = pw2 @ mw1[256:288,:]  (32x128), b_c = pb2 @ mw1[256:288,:] + mb1
// also detect whether edge_index arrived as int64 (viewed as int32 pairs)
// ---------------------------------------------------------------------------
__global__ void prep_kernel(const float* __restrict__ pw2, const float* __restrict__ pb2,
                            const float* __restrict__ mw1, const float* __restrict__ mb1,
                            const int* __restrict__ ei,
                            float* __restrict__ Wpc, float* __restrict__ bc,
                            int* __restrict__ flag)
{
    int tid = threadIdx.x;
    for (int idx = tid; idx < 32 * 128; idx += 256) {
        int j = idx >> 7, k = idx & 127;
        float s = 0.f;
        #pragma unroll 8
        for (int i = 0; i < 32; ++i) s += pw2[j * 32 + i] * mw1[(256 + i) * 128 + k];
        Wpc[idx] = s;
    }
    if (tid < 128) {
        float s = mb1[tid];
        #pragma unroll 8
        for (int i = 0; i < 32; ++i) s += pb2[i] * mw1[(256 + i) * 128 + tid];
        bc[tid] = s;
    }
    if (tid == 0) {
        int z = 1;
        for (int k = 0; k < 16; ++k) if (ei[2 * k + 1] != 0) z = 0;
        *flag = z;
    }
}

// ---------------------------------------------------------------------------
// counting sort of edges by destination (col)
// ---------------------------------------------------------------------------
__global__ void hist_kernel(const int* __restrict__ ei, const int* __restrict__ flag,
                            int* __restrict__ cnt)
{
    int e = blockIdx.x * 256 + threadIdx.x;
    if (e >= NE) return;
    int c = flag[0] ? ei[2 * NE + 2 * e] : ei[NE + e];
    atomicAdd(&cnt[c], 1);
}

__global__ void scan1_kernel(const int* __restrict__ cnt, int* __restrict__ cursor,
                             int* __restrict__ bsum)
{
    __shared__ int tot[256];
    int b = blockIdx.x, t = threadIdx.x;
    int i0 = b * SCAN_CHUNK + t * 4;
    int v[4];
    #pragma unroll
    for (int k = 0; k < 4; ++k) v[k] = (i0 + k < NN) ? cnt[i0 + k] : 0;
    tot[t] = v[0] + v[1] + v[2] + v[3];
    __syncthreads();
    if (t == 0) {
        int run = 0;
        for (int i = 0; i < 256; ++i) { int x = tot[i]; tot[i] = run; run += x; }
        bsum[b] = run;
    }
    __syncthreads();
    int p = tot[t];
    #pragma unroll
    for (int k = 0; k < 4; ++k) {
        if (i0 + k < NN) cursor[i0 + k] = p;
        p += v[k];
    }
}

__global__ void scan2_kernel(int* __restrict__ bsum)
{
    if (threadIdx.x == 0) {
        int run = 0;
        for (int i = 0; i < SCAN_BLOCKS; ++i) { int x = bsum[i]; bsum[i] = run; run += x; }
    }
}

__global__ void scan3_kernel(int* __restrict__ cursor, const int* __restrict__ bsum)
{
    int b = blockIdx.x, t = threadIdx.x;
    int carry = bsum[b];
    int i0 = b * SCAN_CHUNK + t * 4;
    #pragma unroll
    for (int k = 0; k < 4; ++k)
        if (i0 + k < NN) cursor[i0 + k] += carry;
}

__global__ void scatter_kernel(const int* __restrict__ ei, const int* __restrict__ flag,
                               int* __restrict__ cursor, int2* __restrict__ sRC)
{
    int e = blockIdx.x * 256 + threadIdx.x;
    if (e >= NE) return;
    int r, c;
    if (flag[0]) { r = ei[2 * e]; c = ei[2 * NE + 2 * e]; }
    else         { r = ei[e];     c = ei[NE + e]; }
    int p = atomicAdd(&cursor[c], 1);
    sRC[p] = make_int2(r, c);
}

// ---------------------------------------------------------------------------
// stage 1: xa = bf16(x @ mw1[0:128,:]), xb = bf16(x @ mw1[128:256,:])
// ---------------------------------------------------------------------------
__global__ __launch_bounds__(256, 2) void node_pre_kernel(
    const float* __restrict__ x, const float* __restrict__ mw1,
    unsigned short* __restrict__ xa, unsigned short* __restrict__ xb)
{
    __shared__ __align__(16) unsigned short sB[256 * 136]; // [c][k] col-major, pad 136

    int tid = threadIdx.x;
    for (int idx = tid; idx < 256 * 128; idx += 256) {
        int c = idx & 255, k = idx >> 8;
        float v = (c < 128) ? mw1[k * 128 + c] : mw1[(128 + k) * 128 + (c - 128)];
        sB[c * 136 + k] = f2bf(v);
    }
    __syncthreads();

    int lane = tid & 63, wv = tid >> 6;
    int r16 = lane & 15, g4 = lane >> 4;
    int ntile = (NN + 63) >> 6; // 782

    for (int t = blockIdx.x; t < ntile; t += gridDim.x) {
        int r0 = t * 64 + wv * 16;
        int row = r0 + r16;
        int rowc = row < NN ? row : NN - 1;
        s16x8 a[4];
        #pragma unroll
        for (int ks = 0; ks < 4; ++ks) {
            const float* p = &x[rowc * HD + ks * 32 + g4 * 8];
            float4 v0 = *(const float4*)p;
            float4 v1 = *(const float4*)(p + 4);
            s16x8 av;
            av[0] = f2bf(v0.x); av[1] = f2bf(v0.y); av[2] = f2bf(v0.z); av[3] = f2bf(v0.w);
            av[4] = f2bf(v1.x); av[5] = f2bf(v1.y); av[6] = f2bf(v1.z); av[7] = f2bf(v1.w);
            a[ks] = av;
        }
        #pragma unroll
        for (int tc = 0; tc < 16; ++tc) {
            f32x4 acc = {0.f, 0.f, 0.f, 0.f};
            #pragma unroll
            for (int ks = 0; ks < 4; ++ks) {
                s16x8 b = *(const s16x8*)&sB[(tc * 16 + r16) * 136 + ks * 32 + g4 * 8];
                acc = __builtin_amdgcn_mfma_f32_16x16x32_bf16(a[ks], b, acc, 0, 0, 0);
            }
            #pragma unroll
            for (int j = 0; j < 4; ++j) {
                int r = r0 + g4 * 4 + j;
                if (r < NN) {
                    int c = tc * 16 + r16;
                    if (c < 128) xa[r * HD + c] = f2bf(acc[j]);
                    else         xb[r * HD + (c - 128)] = f2bf(acc[j]);
                }
            }
        }
    }
}

// ---------------------------------------------------------------------------
// stage 2 (edges, SORTED by col): wave-private 16-edge tiles, ZERO barriers
// in the main loop; software-pipelined meta + gather prefetch.
// ---------------------------------------------------------------------------
__global__ __launch_bounds__(256, 2) void edge_kernel(
    const float* __restrict__ pos, const int2* __restrict__ sRC,
    const float* __restrict__ pw1, const float* __restrict__ pb1,
    const float* __restrict__ mw2, const float* __restrict__ mb2,
    const unsigned short* __restrict__ xa, const unsigned short* __restrict__ xb,
    const float* __restrict__ Wpc, const float* __restrict__ bc,
    float* __restrict__ agg)
{
    __shared__ __align__(16) unsigned short sB[128 * 136];       // mw2 [c][k], shared RO
    __shared__ __align__(16) unsigned short sSTG[4][16 * 136];   // per-wave staging/msg
    __shared__ __align__(16) unsigned short sHR[4][16 * 136];    // per-wave relu(h1)
    __shared__ int sECs[4][16];                                  // per-wave dest cols

    int tid = threadIdx.x;
    for (int idx = tid; idx < 128 * 128; idx += 256) {
        int c = idx & 127, k = idx >> 7;
        sB[c * 136 + k] = f2bf(mw2[k * 128 + c]);
    }
    __syncthreads();  // only barrier; waves are independent from here on

    int lane = tid & 63, wv = tid >> 6;
    int r16 = lane & 15, g4 = lane >> 4;
    unsigned short* stg = sSTG[wv];
    unsigned short* hrb = sHR[wv];
    int* secw = sECs[wv];

    // ---- per-lane constant preloads (registers)
    s16x8 wr[8];
    #pragma unroll
    for (int tc = 0; tc < 8; ++tc) {
        s16x8 w;
        #pragma unroll
        for (int i = 0; i < 8; ++i)
            w[i] = (short)f2bf(Wpc[(g4 * 8 + i) * 128 + tc * 16 + r16]);
        wr[tc] = w;
    }
    float pw10[8], pw11[8], pw12[8], pb1r[8], bcg[8], mb2r[8];
    #pragma unroll
    for (int i = 0; i < 8; ++i) {
        int k = g4 * 8 + i;
        pw10[i] = pw1[k]; pw11[i] = pw1[32 + k]; pw12[i] = pw1[64 + k];
        pb1r[i] = pb1[k];
        bcg[i] = bc[r16 * 8 + i];
    }
    #pragma unroll
    for (int tc = 0; tc < 8; ++tc) mb2r[tc] = mb2[tc * 16 + r16];

    const int NW = gridDim.x * 4;
    const int NT = NE / 16;  // 50000
    int gw = blockIdx.x * 4 + wv;

    if (gw >= NT) return;

    // ---- prologue: meta + gathers for first tile
    int2 rc = sRC[gw * 16 + r16];
    int2 g0 = sRC[gw * 16 + 0 + g4];
    int2 g1 = sRC[gw * 16 + 4 + g4];
    int2 g2 = sRC[gw * 16 + 8 + g4];
    int2 g3 = sRC[gw * 16 + 12 + g4];
    float dp0 = pos[rc.x * 3 + 0] - pos[rc.y * 3 + 0];
    float dp1 = pos[rc.x * 3 + 1] - pos[rc.y * 3 + 1];
    float dp2 = pos[rc.x * 3 + 2] - pos[rc.y * 3 + 2];
    s16x8 ga[4], gb[4];
    ga[0] = *(const s16x8*)&xa[(size_t)g0.x * HD + r16 * 8];
    ga[1] = *(const s16x8*)&xa[(size_t)g1.x * HD + r16 * 8];
    ga[2] = *(const s16x8*)&xa[(size_t)g2.x * HD + r16 * 8];
    ga[3] = *(const s16x8*)&xa[(size_t)g3.x * HD + r16 * 8];
    gb[0] = *(const s16x8*)&xb[(size_t)g0.y * HD + r16 * 8];
    gb[1] = *(const s16x8*)&xb[(size_t)g1.y * HD + r16 * 8];
    gb[2] = *(const s16x8*)&xb[(size_t)g2.y * HD + r16 * 8];
    gb[3] = *(const s16x8*)&xb[(size_t)g3.y * HD + r16 * 8];

    for (int t = gw; t < NT; t += NW) {
        int tn = t + NW;
        bool hn = tn < NT;

        // ---- 1. staging: bf16(xa[row]+xb[col]+bc) -> stg
        #pragma unroll
        for (int s = 0; s < 4; ++s) {
            s16x8 o;
            #pragma unroll
            for (int i = 0; i < 8; ++i)
                o[i] = (short)f2bf(bf2f((unsigned short)ga[s][i]) +
                                   bf2f((unsigned short)gb[s][i]) + bcg[i]);
            *(s16x8*)&stg[(s * 4 + g4) * 136 + r16 * 8] = o;
        }
        if (lane < 16) secw[lane] = rc.y;
        WFENCE();

        // ---- 2. issue next-tile meta (consumed at step 6/8)
        int2 rcN, gN0, gN1, gN2, gN3;
        if (hn) {
            rcN = sRC[tn * 16 + r16];
            gN0 = sRC[tn * 16 + 0 + g4];
            gN1 = sRC[tn * 16 + 4 + g4];
            gN2 = sRC[tn * 16 + 8 + g4];
            gN3 = sRC[tn * 16 + 12 + g4];
        }

        // ---- 3. pos-MLP layer1 directly in A-frag layout
        s16x8 apf;
        #pragma unroll
        for (int i = 0; i < 8; ++i) {
            float v = fmaf(dp0, pw10[i], fmaf(dp1, pw11[i], fmaf(dp2, pw12[i], pb1r[i])));
            apf[i] = (short)f2bf(fmaxf(v, 0.f));
        }

        // ---- 4. GEMM1: h1 = pf@Wpc + staging ; HR = relu
        #pragma unroll
        for (int tc = 0; tc < 8; ++tc) {
            f32x4 z = {0.f, 0.f, 0.f, 0.f};
            f32x4 a1 = __builtin_amdgcn_mfma_f32_16x16x32_bf16(apf, wr[tc], z, 0, 0, 0);
            #pragma unroll
            for (int j = 0; j < 4; ++j) {
                int e = g4 * 4 + j, col = tc * 16 + r16;
                float v = a1[j] + bf2f(stg[e * 136 + col]);
                hrb[e * 136 + col] = f2bf(fmaxf(v, 0.f));
            }
        }
        WFENCE();

        // ---- 5. A-frags of GEMM2 from HR
        s16x8 a2[4];
        #pragma unroll
        for (int ks = 0; ks < 4; ++ks)
            a2[ks] = *(const s16x8*)&hrb[r16 * 136 + ks * 32 + g4 * 8];

        // ---- 6. next-tile pos diffs (meta arrived by now)
        float dp0N = 0.f, dp1N = 0.f, dp2N = 0.f;
        if (hn) {
            dp0N = pos[rcN.x * 3 + 0] - pos[rcN.y * 3 + 0];
            dp1N = pos[rcN.x * 3 + 1] - pos[rcN.y * 3 + 1];
            dp2N = pos[rcN.x * 3 + 2] - pos[rcN.y * 3 + 2];
        }

        // ---- 7. GEMM2: msg = HR @ mw2 + mb2 -> stg (bf16, overlay)
        #pragma unroll
        for (int tc = 0; tc < 8; ++tc) {
            f32x4 acc = {mb2r[tc], mb2r[tc], mb2r[tc], mb2r[tc]};
            #pragma unroll
            for (int ks = 0; ks < 4; ++ks) {
                s16x8 b = *(const s16x8*)&sB[(tc * 16 + r16) * 136 + ks * 32 + g4 * 8];
                acc = __builtin_amdgcn_mfma_f32_16x16x32_bf16(a2[ks], b, acc, 0, 0, 0);
            }
            #pragma unroll
            for (int j = 0; j < 4; ++j)
                stg[(g4 * 4 + j) * 136 + tc * 16 + r16] = f2bf(acc[j]);
        }
        WFENCE();

        // ---- 8. issue next-tile gathers (latency hides under segred)
        if (hn) {
            ga[0] = *(const s16x8*)&xa[(size_t)gN0.x * HD + r16 * 8];
            ga[1] = *(const s16x8*)&xa[(size_t)gN1.x * HD + r16 * 8];
            ga[2] = *(const s16x8*)&xa[(size_t)gN2.x * HD + r16 * 8];
            ga[3] = *(const s16x8*)&xa[(size_t)gN3.x * HD + r16 * 8];
            gb[0] = *(const s16x8*)&xb[(size_t)gN0.y * HD + r16 * 8];
            gb[1] = *(const s16x8*)&xb[(size_t)gN1.y * HD + r16 * 8];
            gb[2] = *(const s16x8*)&xb[(size_t)gN2.y * HD + r16 * 8];
            gb[3] = *(const s16x8*)&xb[(size_t)gN3.y * HD + r16 * 8];
        }

        // ---- 9. segmented reduce over sorted cols -> atomics
        {
            int f0 = lane, f1 = lane + 64;
            int cur = secw[0];
            float run0 = bf2f(stg[f0]);
            float run1 = bf2f(stg[f1]);
            #pragma unroll
            for (int e = 1; e < 16; ++e) {
                int c = secw[e];
                float v0 = bf2f(stg[e * 136 + f0]);
                float v1 = bf2f(stg[e * 136 + f1]);
                if (c != cur) {  // wave-uniform branch
                    unsafeAtomicAdd(&agg[(size_t)cur * HD + f0], run0);
                    unsafeAtomicAdd(&agg[(size_t)cur * HD + f1], run1);
                    cur = c; run0 = v0; run1 = v1;
                } else { run0 += v0; run1 += v1; }
            }
            unsafeAtomicAdd(&agg[(size_t)cur * HD + f0], run0);
            unsafeAtomicAdd(&agg[(size_t)cur * HD + f1], run1);
        }
        WFENCE();

        rc = rcN; dp0 = dp0N; dp1 = dp1N; dp2 = dp2N;
    }
}

// ---------------------------------------------------------------------------
// stage 3a: t = bf16(relu(x@uw1a + agg@uw1b + ub1))   [N x 128]
// ---------------------------------------------------------------------------
__global__ __launch_bounds__(256, 2) void upd1_kernel(
    const float* __restrict__ x, const float* __restrict__ agg,
    const float* __restrict__ uw1, const float* __restrict__ ub1,
    unsigned short* __restrict__ tbuf)
{
    __shared__ __align__(16) unsigned short sB1[128 * 264]; // uw1 [c][k<256]

    int tid = threadIdx.x;
    for (int idx = tid; idx < 256 * 128; idx += 256) {
        int c = idx & 127, k = idx >> 7;
        sB1[c * 264 + k] = f2bf(uw1[k * 128 + c]);
    }
    __syncthreads();

    int lane = tid & 63, wv = tid >> 6;
    int r16 = lane & 15, g4 = lane >> 4;
    float ub1r[8];
    #pragma unroll
    for (int tc = 0; tc < 8; ++tc) ub1r[tc] = ub1[tc * 16 + r16];

    const int NW = gridDim.x * 4;
    const int NT = NN / 16;  // 3125
    for (int t = blockIdx.x * 4 + wv; t < NT; t += NW) {
        int r0 = t * 16;
        int row = r0 + r16;
        s16x8 a[8];
        #pragma unroll
        for (int ks = 0; ks < 8; ++ks) {
            const float* p = (ks < 4) ? &x[(size_t)row * HD + ks * 32 + g4 * 8]
                                      : &agg[(size_t)row * HD + (ks - 4) * 32 + g4 * 8];
            float4 v0 = *(const float4*)p;
            float4 v1 = *(const float4*)(p + 4);
            s16x8 av;
            av[0] = f2bf(v0.x); av[1] = f2bf(v0.y); av[2] = f2bf(v0.z); av[3] = f2bf(v0.w);
            av[4] = f2bf(v1.x); av[5] = f2bf(v1.y); av[6] = f2bf(v1.z); av[7] = f2bf(v1.w);
            a[ks] = av;
        }
        #pragma unroll
        for (int tc = 0; tc < 8; ++tc) {
            int col = tc * 16 + r16;
            float bv = ub1r[tc];
            f32x4 acc = {bv, bv, bv, bv};
            #pragma unroll
            for (int ks = 0; ks < 8; ++ks) {
                s16x8 b = *(const s16x8*)&sB1[col * 264 + ks * 32 + g4 * 8];
                acc = __builtin_amdgcn_mfma_f32_16x16x32_bf16(a[ks], b, acc, 0, 0, 0);
            }
            #pragma unroll
            for (int j = 0; j < 4; ++j)
                tbuf[(size_t)(r0 + g4 * 4 + j) * HD + col] = f2bf(fmaxf(acc[j], 0.f));
        }
    }
}

// ---------------------------------------------------------------------------
// stage 3b: out = t @ uw2 + ub2
// ---------------------------------------------------------------------------
__global__ __launch_bounds__(256, 4) void upd2_kernel(
    const unsigned short* __restrict__ tbuf,
    const float* __restrict__ uw2, const float* __restrict__ ub2,
    float* __restrict__ out)
{
    __shared__ __align__(16) unsigned short sB2[128 * 136];

    int tid = threadIdx.x;
    for (int idx = tid; idx < 128 * 128; idx += 256) {
        int c = idx & 127, k = idx >> 7;
        sB2[c * 136 + k] = f2bf(uw2[k * 128 + c]);
    }
    __syncthreads();

    int lane = tid & 63, wv = tid >> 6;
    int r16 = lane & 15, g4 = lane >> 4;
    float ub2r[8];
    #pragma unroll
    for (int tc = 0; tc < 8; ++tc) ub2r[tc] = ub2[tc * 16 + r16];

    const int NW = gridDim.x * 4;
    const int NT = NN / 16;  // 3125
    for (int t = blockIdx.x * 4 + wv; t < NT; t += NW) {
        int r0 = t * 16;
        s16x8 a[4];
        #pragma unroll
        for (int ks = 0; ks < 4; ++ks)
            a[ks] = *(const s16x8*)&tbuf[(size_t)(r0 + r16) * HD + ks * 32 + g4 * 8];
        #pragma unroll
        for (int tc = 0; tc < 8; ++tc) {
            int col = tc * 16 + r16;
            float bv = ub2r[tc];
            f32x4 acc = {bv, bv, bv, bv};
            #pragma unroll
            for (int ks = 0; ks < 4; ++ks) {
                s16x8 b = *(const s16x8*)&sB2[col * 136 + ks * 32 + g4 * 8];
                acc = __builtin_amdgcn_mfma_f32_16x16x32_bf16(a[ks], b, acc, 0, 0, 0);
            }
            #pragma unroll
            for (int j = 0; j < 4; ++j)
                out[(size_t)(r0 + g4 * 4 + j) * HD + col] = acc[j];
        }
    }
}

// ---------------------------------------------------------------------------
extern "C" void kernel_launch(void* const* d_in, const int* in_sizes, int n_in,
                              void* d_out, int out_size, void* d_ws, size_t ws_size,
                              hipStream_t stream)
{
    const float* x   = (const float*)d_in[0];
    const float* pos = (const float*)d_in[1];
    const int*   ei  = (const int*)d_in[2];
    const float* pw1 = (const float*)d_in[3];
    const float* pb1 = (const float*)d_in[4];
    const float* pw2 = (const float*)d_in[5];
    const float* pb2 = (const float*)d_in[6];
    const float* mw1 = (const float*)d_in[7];
    const float* mb1 = (const float*)d_in[8];
    const float* mw2 = (const float*)d_in[9];
    const float* mb2 = (const float*)d_in[10];
    const float* uw1 = (const float*)d_in[11];
    const float* ub1 = (const float*)d_in[12];
    const float* uw2 = (const float*)d_in[13];
    const float* ub2 = (const float*)d_in[14];
    float* out = (float*)d_out;

    char* ws = (char*)d_ws;
    float*          agg    = (float*)(ws);                      // 25,600,000 B
    unsigned short* xa     = (unsigned short*)(ws + 25600000);  // 12,800,000 B (tbuf overlay)
    unsigned short* xb     = (unsigned short*)(ws + 38400000);  // 12,800,000 B
    float*          Wpc    = (float*)(ws + 51200000);           // 16,384 B
    float*          bcv    = (float*)(ws + 51216384);           // 512 B
    int*            flag   = (int*)(ws + 51216896);             // 256 B
    int*            cnt    = (int*)(ws + 51217152);             // 200,704 B
    int*            cursor = (int*)(ws + 51417856);             // 200,704 B
    int*            bsum   = (int*)(ws + 51618560);             // 256 B
    int2*           sRC    = (int2*)(ws + 51618816);            // 6,400,000 B -> ~58 MB

    unsigned short* tbuf = xa;  // xa dead after edge_kernel; reuse for t

    hipMemsetAsync(agg, 0, (size_t)NN * HD * sizeof(float), stream);
    hipMemsetAsync(cnt, 0, SCAN_BLOCKS * SCAN_CHUNK * sizeof(int), stream);
    prep_kernel<<<1, 256, 0, stream>>>(pw2, pb2, mw1, mb1, ei, Wpc, bcv, flag);
    hist_kernel<<<NE / 256, 256, 0, stream>>>(ei, flag, cnt);
    scan1_kernel<<<SCAN_BLOCKS, 256, 0, stream>>>(cnt, cursor, bsum);
    scan2_kernel<<<1, 64, 0, stream>>>(bsum);
    scan3_kernel<<<SCAN_BLOCKS, 256, 0, stream>>>(cursor, bsum);
    scatter_kernel<<<NE / 256, 256, 0, stream>>>(ei, flag, cursor, sRC);
    node_pre_kernel<<<512, 256, 0, stream>>>(x, mw1, xa, xb);
    edge_kernel<<<512, 256, 0, stream>>>(pos, sRC, pw1, pb1, mw2, mb2, xa, xb, Wpc, bcv, agg);
    upd1_kernel<<<512, 256, 0, stream>>>(x, agg, uw1, ub1, tbuf);
    upd2_kernel<<<1024, 256, 0, stream>>>(tbuf, uw2, ub2, out);
}

// Round 4
// 335.548 us; speedup vs baseline: 1.2719x; 1.0158x over previous
//
#include <hip/hip_runtime.h>
#include <hip/hip_bf16.h>

#define NN 50000
#define NE 800000
#define HD 128
#define SCAN_CHUNK 1024
#define SCAN_BLOCKS ((NN + SCAN_CHUNK - 1) / SCAN_CHUNK)  // 49

typedef __attribute__((ext_vector_type(8))) short s16x8;
typedef __attribute__((ext_vector_type(4))) float f32x4;

static __device__ __forceinline__ unsigned short f2bf(float f) {
    unsigned int u = __float_as_uint(f);
    u = (u + 0x7FFFu + ((u >> 16) & 1u)) >> 16;
    return (unsigned short)u;
}
static __device__ __forceinline__ float bf2f(unsigned short h) {
    return __uint_as_float(((unsigned int)h) << 16);
}
// packed f32 pair -> bf16x2 (compiler may fuse to v_cvt_pk_bf16_f32)
static __device__ __forceinline__ unsigned int f2bf2(float lo, float hi) {
    __hip_bfloat162 h = __float22bfloat162_rn(make_float2(lo, hi));
    return *reinterpret_cast<unsigned int*>(&h);
}

// wave-level LDS fence: drain this wave's LDS ops, block compiler reordering.
#define WFENCE() do { asm volatile("s_waitcnt lgkmcnt(0)" ::: "memory"); \
                      __builtin_amdgcn_sched_barrier(0); } while (0)

// ---------------------------------------------------------------------------
// prep: Wpc = pw2 @ mw1[256:288,:]  (32x128), b_c = pb2 @ mw1[256:288,:] + mb1
// ---------------------------------------------------------------------------
__global__ void prep_kernel(const float* __restrict__ pw2, const float* __restrict__ pb2,
                            const float* __restrict__ mw1, const float* __restrict__ mb1,
                            const int* __restrict__ ei,
                            float* __restrict__ Wpc, float* __restrict__ bc,
                            int* __restrict__ flag)
{
    int tid = threadIdx.x;
    for (int idx = tid; idx < 32 * 128; idx += 256) {
        int j = idx >> 7, k = idx & 127;
        float s = 0.f;
        #pragma unroll 8
        for (int i = 0; i < 32; ++i) s += pw2[j * 32 + i] * mw1[(256 + i) * 128 + k];
        Wpc[idx] = s;
    }
    if (tid < 128) {
        float s = mb1[tid];
        #pragma unroll 8
        for (int i = 0; i < 32; ++i) s += pb2[i] * mw1[(256 + i) * 128 + tid];
        bc[tid] = s;
    }
    if (tid == 0) {
        int z = 1;
        for (int k = 0; k < 16; ++k) if (ei[2 * k + 1] != 0) z = 0;
        *flag = z;
    }
}

// ---------------------------------------------------------------------------
// counting sort of edges by destination (col)
// ---------------------------------------------------------------------------
__global__ void hist_kernel(const int* __restrict__ ei, const int* __restrict__ flag,
                            int* __restrict__ cnt)
{
    int e = blockIdx.x * 256 + threadIdx.x;
    if (e >= NE) return;
    int c = flag[0] ? ei[2 * NE + 2 * e] : ei[NE + e];
    atomicAdd(&cnt[c], 1);
}

__global__ void scan1_kernel(const int* __restrict__ cnt, int* __restrict__ cursor,
                             int* __restrict__ bsum)
{
    __shared__ int tot[256];
    int b = blockIdx.x, t = threadIdx.x;
    int i0 = b * SCAN_CHUNK + t * 4;
    int v[4];
    #pragma unroll
    for (int k = 0; k < 4; ++k) v[k] = (i0 + k < NN) ? cnt[i0 + k] : 0;
    tot[t] = v[0] + v[1] + v[2] + v[3];
    __syncthreads();
    if (t == 0) {
        int run = 0;
        for (int i = 0; i < 256; ++i) { int x = tot[i]; tot[i] = run; run += x; }
        bsum[b] = run;
    }
    __syncthreads();
    int p = tot[t];
    #pragma unroll
    for (int k = 0; k < 4; ++k) {
        if (i0 + k < NN) cursor[i0 + k] = p;
        p += v[k];
    }
}

__global__ void scan2_kernel(int* __restrict__ bsum)
{
    if (threadIdx.x == 0) {
        int run = 0;
        for (int i = 0; i < SCAN_BLOCKS; ++i) { int x = bsum[i]; bsum[i] = run; run += x; }
    }
}

__global__ void scan3_kernel(int* __restrict__ cursor, const int* __restrict__ bsum)
{
    int b = blockIdx.x, t = threadIdx.x;
    int carry = bsum[b];
    int i0 = b * SCAN_CHUNK + t * 4;
    #pragma unroll
    for (int k = 0; k < 4; ++k)
        if (i0 + k < NN) cursor[i0 + k] += carry;
}

__global__ void scatter_kernel(const int* __restrict__ ei, const int* __restrict__ flag,
                               int* __restrict__ cursor, int2* __restrict__ sRC)
{
    int e = blockIdx.x * 256 + threadIdx.x;
    if (e >= NE) return;
    int r, c;
    if (flag[0]) { r = ei[2 * e]; c = ei[2 * NE + 2 * e]; }
    else         { r = ei[e];     c = ei[NE + e]; }
    int p = atomicAdd(&cursor[c], 1);
    sRC[p] = make_int2(r, c);
}

// ---------------------------------------------------------------------------
// stage 1: xa = bf16(x @ mw1[0:128,:]), xb = bf16(x @ mw1[128:256,:])
// 16-row wave tiles; coalesced bf16 stores via per-wave LDS staging.
// ---------------------------------------------------------------------------
__global__ __launch_bounds__(256, 2) void node_pre_kernel(
    const float* __restrict__ x, const float* __restrict__ mw1,
    unsigned short* __restrict__ xa, unsigned short* __restrict__ xb)
{
    __shared__ __align__(16) unsigned short sB[256 * 136];   // [c<256][k<128]
    __shared__ __align__(16) unsigned short sSt[4][16 * 64]; // per-wave col-half stage

    int tid = threadIdx.x;
    for (int idx = tid; idx < 256 * 128; idx += 256) {
        int c = idx & 255, k = idx >> 8;
        float v = (c < 128) ? mw1[k * 128 + c] : mw1[(128 + k) * 128 + (c - 128)];
        sB[c * 136 + k] = f2bf(v);
    }
    __syncthreads();

    int lane = tid & 63, wv = tid >> 6;
    int r16 = lane & 15, g4 = lane >> 4;
    unsigned short* st = sSt[wv];
    const int NT = NN / 16;  // 3125 exactly

    for (int t = blockIdx.x * 4 + wv; t < NT; t += gridDim.x * 4) {
        int r0 = t * 16;
        int row = r0 + r16;
        s16x8 a[4];
        #pragma unroll
        for (int ks = 0; ks < 4; ++ks) {
            const float* p = &x[(size_t)row * HD + ks * 32 + g4 * 8];
            float4 v0 = *(const float4*)p;
            float4 v1 = *(const float4*)(p + 4);
            union { s16x8 v; unsigned int u[4]; } av;
            av.u[0] = f2bf2(v0.x, v0.y); av.u[1] = f2bf2(v0.z, v0.w);
            av.u[2] = f2bf2(v1.x, v1.y); av.u[3] = f2bf2(v1.z, v1.w);
            a[ks] = av.v;
        }
        // 4 groups of 4 tc: {xa lo, xa hi, xb lo, xb hi}
        #pragma unroll
        for (int grp = 0; grp < 4; ++grp) {
            #pragma unroll
            for (int tc2 = 0; tc2 < 4; ++tc2) {
                int tc = grp * 4 + tc2;
                int col = tc * 16 + r16;  // 0..255
                f32x4 acc = {0.f, 0.f, 0.f, 0.f};
                #pragma unroll
                for (int ks = 0; ks < 4; ++ks) {
                    s16x8 b = *(const s16x8*)&sB[col * 136 + ks * 32 + g4 * 8];
                    acc = __builtin_amdgcn_mfma_f32_16x16x32_bf16(a[ks], b, acc, 0, 0, 0);
                }
                #pragma unroll
                for (int j = 0; j < 4; ++j)
                    st[(g4 * 4 + j) * 64 + tc2 * 16 + r16] = f2bf(acc[j]);
            }
            WFENCE();
            unsigned short* dst = (grp < 2) ? xa : xb;
            int ch = (grp & 1) * 64;
            #pragma unroll
            for (int i = 0; i < 2; ++i) {
                int idx = i * 512 + lane * 8;       // elem in [16][64]
                int rr = idx >> 6, cc = idx & 63;
                *(s16x8*)&dst[(size_t)(r0 + rr) * HD + ch + cc] = *(const s16x8*)&st[idx];
            }
            WFENCE();
        }
    }
}

// ---------------------------------------------------------------------------
// stage 2 (edges, SORTED by col): wave-private 16-edge tiles, zero block
// barriers in main loop, merged LDS buffer (3 blocks/CU), chunked tiles.
// ---------------------------------------------------------------------------
__global__ __launch_bounds__(256, 3) void edge_kernel(
    const float* __restrict__ pos, const int2* __restrict__ sRC,
    const float* __restrict__ pw1, const float* __restrict__ pb1,
    const float* __restrict__ mw2, const float* __restrict__ mb2,
    const unsigned short* __restrict__ xa, const unsigned short* __restrict__ xb,
    const float* __restrict__ Wpc, const float* __restrict__ bc,
    float* __restrict__ agg)
{
    __shared__ __align__(16) unsigned short sB[128 * 136];     // mw2 [c][k], shared RO
    __shared__ __align__(16) unsigned short sT[4][16 * 136];   // per-wave stg/HR/msg
    __shared__ int sECs[4][16];

    int tid = threadIdx.x;
    for (int idx = tid; idx < 128 * 128; idx += 256) {
        int c = idx & 127, k = idx >> 7;
        sB[c * 136 + k] = f2bf(mw2[k * 128 + c]);
    }
    __syncthreads();  // only block barrier

    int lane = tid & 63, wv = tid >> 6;
    int r16 = lane & 15, g4 = lane >> 4;
    unsigned short* stg = sT[wv];
    int* secw = sECs[wv];

    // per-lane constant preloads
    s16x8 wr[8];
    #pragma unroll
    for (int tc = 0; tc < 8; ++tc) {
        s16x8 w;
        #pragma unroll
        for (int i = 0; i < 8; ++i)
            w[i] = (short)f2bf(Wpc[(g4 * 8 + i) * 128 + tc * 16 + r16]);
        wr[tc] = w;
    }
    float pw10[8], pw11[8], pw12[8], pb1r[8], bcg[8], mb2r[8];
    #pragma unroll
    for (int i = 0; i < 8; ++i) {
        int k = g4 * 8 + i;
        pw10[i] = pw1[k]; pw11[i] = pw1[32 + k]; pw12[i] = pw1[64 + k];
        pb1r[i] = pb1[k];
        bcg[i] = bc[r16 * 8 + i];
    }
    #pragma unroll
    for (int tc = 0; tc < 8; ++tc) mb2r[tc] = mb2[tc * 16 + r16];

    // chunked tile assignment: contiguous sorted range per wave
    const int NT = NE / 16;  // 50000
    const int nwaves = gridDim.x * 4;
    const int per = (NT + nwaves - 1) / nwaves;
    int t0 = (blockIdx.x * 4 + wv) * per;
    int t1 = t0 + per; if (t1 > NT) t1 = NT;
    if (t0 >= t1) return;

    // prologue: meta + gathers for first tile
    int2 rc = sRC[t0 * 16 + r16];
    int2 g0 = sRC[t0 * 16 + 0 + g4];
    int2 g1 = sRC[t0 * 16 + 4 + g4];
    int2 g2 = sRC[t0 * 16 + 8 + g4];
    int2 g3 = sRC[t0 * 16 + 12 + g4];
    float dp0 = pos[rc.x * 3 + 0] - pos[rc.y * 3 + 0];
    float dp1 = pos[rc.x * 3 + 1] - pos[rc.y * 3 + 1];
    float dp2 = pos[rc.x * 3 + 2] - pos[rc.y * 3 + 2];
    s16x8 ga[4], gb[4];
    ga[0] = *(const s16x8*)&xa[(size_t)g0.x * HD + r16 * 8];
    ga[1] = *(const s16x8*)&xa[(size_t)g1.x * HD + r16 * 8];
    ga[2] = *(const s16x8*)&xa[(size_t)g2.x * HD + r16 * 8];
    ga[3] = *(const s16x8*)&xa[(size_t)g3.x * HD + r16 * 8];
    gb[0] = *(const s16x8*)&xb[(size_t)g0.y * HD + r16 * 8];
    gb[1] = *(const s16x8*)&xb[(size_t)g1.y * HD + r16 * 8];
    gb[2] = *(const s16x8*)&xb[(size_t)g2.y * HD + r16 * 8];
    gb[3] = *(const s16x8*)&xb[(size_t)g3.y * HD + r16 * 8];

    for (int t = t0; t < t1; ++t) {
        int tn = t + 1;
        bool hn = tn < t1;

        // ---- 1. staging: bf16(xa[row]+xb[col]+bc) -> stg
        #pragma unroll
        for (int s = 0; s < 4; ++s) {
            union { s16x8 v; unsigned int u[4]; } o;
            #pragma unroll
            for (int i2 = 0; i2 < 4; ++i2) {
                float v0 = bf2f((unsigned short)ga[s][2 * i2]) +
                           bf2f((unsigned short)gb[s][2 * i2]) + bcg[2 * i2];
                float v1 = bf2f((unsigned short)ga[s][2 * i2 + 1]) +
                           bf2f((unsigned short)gb[s][2 * i2 + 1]) + bcg[2 * i2 + 1];
                o.u[i2] = f2bf2(v0, v1);
            }
            *(s16x8*)&stg[(s * 4 + g4) * 136 + r16 * 8] = o.v;
        }
        if (lane < 16) secw[lane] = rc.y;
        WFENCE();

        // ---- 2. next-tile meta
        int2 rcN, gN0, gN1, gN2, gN3;
        if (hn) {
            rcN = sRC[tn * 16 + r16];
            gN0 = sRC[tn * 16 + 0 + g4];
            gN1 = sRC[tn * 16 + 4 + g4];
            gN2 = sRC[tn * 16 + 8 + g4];
            gN3 = sRC[tn * 16 + 12 + g4];
        }

        // ---- 3. pos-MLP layer1 in A-frag layout
        union { s16x8 v; unsigned int u[4]; } apf;
        #pragma unroll
        for (int i2 = 0; i2 < 4; ++i2) {
            int i = 2 * i2;
            float v0 = fmaf(dp0, pw10[i], fmaf(dp1, pw11[i], fmaf(dp2, pw12[i], pb1r[i])));
            float v1 = fmaf(dp0, pw10[i+1], fmaf(dp1, pw11[i+1], fmaf(dp2, pw12[i+1], pb1r[i+1])));
            apf.u[i2] = f2bf2(fmaxf(v0, 0.f), fmaxf(v1, 0.f));
        }

        // ---- 4. GEMM1: h1 = pf@Wpc + stg ; relu -> same buffer (per-lane RMW)
        #pragma unroll
        for (int tc = 0; tc < 8; ++tc) {
            f32x4 z = {0.f, 0.f, 0.f, 0.f};
            f32x4 a1 = __builtin_amdgcn_mfma_f32_16x16x32_bf16(apf.v, wr[tc], z, 0, 0, 0);
            #pragma unroll
            for (int j = 0; j < 4; ++j) {
                int e = g4 * 4 + j, col = tc * 16 + r16;
                float v = a1[j] + bf2f(stg[e * 136 + col]);
                stg[e * 136 + col] = f2bf(fmaxf(v, 0.f));
            }
        }
        WFENCE();

        // ---- 5. A-frags of GEMM2 from HR
        s16x8 a2[4];
        #pragma unroll
        for (int ks = 0; ks < 4; ++ks)
            a2[ks] = *(const s16x8*)&stg[r16 * 136 + ks * 32 + g4 * 8];
        WFENCE();  // a2 in regs before step 7 overwrites

        // ---- 6. next-tile pos diffs
        float dp0N = 0.f, dp1N = 0.f, dp2N = 0.f;
        if (hn) {
            dp0N = pos[rcN.x * 3 + 0] - pos[rcN.y * 3 + 0];
            dp1N = pos[rcN.x * 3 + 1] - pos[rcN.y * 3 + 1];
            dp2N = pos[rcN.x * 3 + 2] - pos[rcN.y * 3 + 2];
        }

        // ---- 7. GEMM2: msg = HR @ mw2 + mb2 -> stg (overlay)
        #pragma unroll
        for (int tc = 0; tc < 8; ++tc) {
            f32x4 acc = {mb2r[tc], mb2r[tc], mb2r[tc], mb2r[tc]};
            #pragma unroll
            for (int ks = 0; ks < 4; ++ks) {
                s16x8 b = *(const s16x8*)&sB[(tc * 16 + r16) * 136 + ks * 32 + g4 * 8];
                acc = __builtin_amdgcn_mfma_f32_16x16x32_bf16(a2[ks], b, acc, 0, 0, 0);
            }
            #pragma unroll
            for (int j = 0; j < 4; ++j)
                stg[(g4 * 4 + j) * 136 + tc * 16 + r16] = f2bf(acc[j]);
        }
        WFENCE();

        // ---- 8. next-tile gathers (hide under segred)
        if (hn) {
            ga[0] = *(const s16x8*)&xa[(size_t)gN0.x * HD + r16 * 8];
            ga[1] = *(const s16x8*)&xa[(size_t)gN1.x * HD + r16 * 8];
            ga[2] = *(const s16x8*)&xa[(size_t)gN2.x * HD + r16 * 8];
            ga[3] = *(const s16x8*)&xa[(size_t)gN3.x * HD + r16 * 8];
            gb[0] = *(const s16x8*)&xb[(size_t)gN0.y * HD + r16 * 8];
            gb[1] = *(const s16x8*)&xb[(size_t)gN1.y * HD + r16 * 8];
            gb[2] = *(const s16x8*)&xb[(size_t)gN2.y * HD + r16 * 8];
            gb[3] = *(const s16x8*)&xb[(size_t)gN3.y * HD + r16 * 8];
        }

        // ---- 9. segmented reduce over sorted cols -> atomics
        {
            int f0 = lane, f1 = lane + 64;
            int cur = secw[0];
            float run0 = bf2f(stg[f0]);
            float run1 = bf2f(stg[f1]);
            #pragma unroll
            for (int e = 1; e < 16; ++e) {
                int c = secw[e];
                float v0 = bf2f(stg[e * 136 + f0]);
                float v1 = bf2f(stg[e * 136 + f1]);
                if (c != cur) {  // wave-uniform
                    unsafeAtomicAdd(&agg[(size_t)cur * HD + f0], run0);
                    unsafeAtomicAdd(&agg[(size_t)cur * HD + f1], run1);
                    cur = c; run0 = v0; run1 = v1;
                } else { run0 += v0; run1 += v1; }
            }
            unsafeAtomicAdd(&agg[(size_t)cur * HD + f0], run0);
            unsafeAtomicAdd(&agg[(size_t)cur * HD + f1], run1);
        }
        WFENCE();

        rc = rcN; dp0 = dp0N; dp1 = dp1N; dp2 = dp2N;
    }
}

// ---------------------------------------------------------------------------
// stage 3a: tbuf = bf16(relu(x@uw1a + agg@uw1b + ub1)), coalesced stores
// ---------------------------------------------------------------------------
__global__ __launch_bounds__(256, 2) void upd1_kernel(
    const float* __restrict__ x, const float* __restrict__ agg,
    const float* __restrict__ uw1, const float* __restrict__ ub1,
    unsigned short* __restrict__ tbuf)
{
    __shared__ __align__(16) unsigned short sB1[128 * 264];   // [c<128][k<256]
    __shared__ __align__(16) unsigned short sSt[4][16 * 64];

    int tid = threadIdx.x;
    for (int idx = tid; idx < 256 * 128; idx += 256) {
        int c = idx & 127, k = idx >> 7;
        sB1[c * 264 + k] = f2bf(uw1[k * 128 + c]);
    }
    __syncthreads();

    int lane = tid & 63, wv = tid >> 6;
    int r16 = lane & 15, g4 = lane >> 4;
    unsigned short* st = sSt[wv];
    float ub1r[8];
    #pragma unroll
    for (int tc = 0; tc < 8; ++tc) ub1r[tc] = ub1[tc * 16 + r16];

    const int NT = NN / 16;  // 3125
    for (int t = blockIdx.x * 4 + wv; t < NT; t += gridDim.x * 4) {
        int r0 = t * 16;
        int row = r0 + r16;
        s16x8 a[8];
        #pragma unroll
        for (int ks = 0; ks < 8; ++ks) {
            const float* p = (ks < 4) ? &x[(size_t)row * HD + ks * 32 + g4 * 8]
                                      : &agg[(size_t)row * HD + (ks - 4) * 32 + g4 * 8];
            float4 v0 = *(const float4*)p;
            float4 v1 = *(const float4*)(p + 4);
            union { s16x8 v; unsigned int u[4]; } av;
            av.u[0] = f2bf2(v0.x, v0.y); av.u[1] = f2bf2(v0.z, v0.w);
            av.u[2] = f2bf2(v1.x, v1.y); av.u[3] = f2bf2(v1.z, v1.w);
            a[ks] = av.v;
        }
        #pragma unroll
        for (int half = 0; half < 2; ++half) {
            #pragma unroll
            for (int tc2 = 0; tc2 < 4; ++tc2) {
                int tc = half * 4 + tc2;
                int col = tc * 16 + r16;
                float bv = ub1r[tc];
                f32x4 acc = {bv, bv, bv, bv};
                #pragma unroll
                for (int ks = 0; ks < 8; ++ks) {
                    s16x8 b = *(const s16x8*)&sB1[col * 264 + ks * 32 + g4 * 8];
                    acc = __builtin_amdgcn_mfma_f32_16x16x32_bf16(a[ks], b, acc, 0, 0, 0);
                }
                #pragma unroll
                for (int j = 0; j < 4; ++j)
                    st[(g4 * 4 + j) * 64 + tc2 * 16 + r16] = f2bf(fmaxf(acc[j], 0.f));
            }
            WFENCE();
            #pragma unroll
            for (int i = 0; i < 2; ++i) {
                int idx = i * 512 + lane * 8;
                int rr = idx >> 6, cc = idx & 63;
                *(s16x8*)&tbuf[(size_t)(r0 + rr) * HD + half * 64 + cc] = *(const s16x8*)&st[idx];
            }
            WFENCE();
        }
    }
}

// ---------------------------------------------------------------------------
// stage 3b: out = tbuf @ uw2 + ub2 (f32 coalesced stores)
// ---------------------------------------------------------------------------
__global__ __launch_bounds__(256, 4) void upd2_kernel(
    const unsigned short* __restrict__ tbuf,
    const float* __restrict__ uw2, const float* __restrict__ ub2,
    float* __restrict__ out)
{
    __shared__ __align__(16) unsigned short sB2[128 * 136];

    int tid = threadIdx.x;
    for (int idx = tid; idx < 128 * 128; idx += 256) {
        int c = idx & 127, k = idx >> 7;
        sB2[c * 136 + k] = f2bf(uw2[k * 128 + c]);
    }
    __syncthreads();

    int lane = tid & 63, wv = tid >> 6;
    int r16 = lane & 15, g4 = lane >> 4;
    float ub2r[8];
    #pragma unroll
    for (int tc = 0; tc < 8; ++tc) ub2r[tc] = ub2[tc * 16 + r16];

    const int NT = NN / 16;  // 3125
    for (int t = blockIdx.x * 4 + wv; t < NT; t += gridDim.x * 4) {
        int r0 = t * 16;
        s16x8 a[4];
        #pragma unroll
        for (int ks = 0; ks < 4; ++ks)
            a[ks] = *(const s16x8*)&tbuf[(size_t)(r0 + r16) * HD + ks * 32 + g4 * 8];
        #pragma unroll
        for (int tc = 0; tc < 8; ++tc) {
            int col = tc * 16 + r16;
            float bv = ub2r[tc];
            f32x4 acc = {bv, bv, bv, bv};
            #pragma unroll
            for (int ks = 0; ks < 4; ++ks) {
                s16x8 b = *(const s16x8*)&sB2[col * 136 + ks * 32 + g4 * 8];
                acc = __builtin_amdgcn_mfma_f32_16x16x32_bf16(a[ks], b, acc, 0, 0, 0);
            }
            #pragma unroll
            for (int j = 0; j < 4; ++j)
                out[(size_t)(r0 + g4 * 4 + j) * HD + col] = acc[j];
        }
    }
}

// ---------------------------------------------------------------------------
extern "C" void kernel_launch(void* const* d_in, const int* in_sizes, int n_in,
                              void* d_out, int out_size, void* d_ws, size_t ws_size,
                              hipStream_t stream)
{
    const float* x   = (const float*)d_in[0];
    const float* pos = (const float*)d_in[1];
    const int*   ei  = (const int*)d_in[2];
    const float* pw1 = (const float*)d_in[3];
    const float* pb1 = (const float*)d_in[4];
    const float* pw2 = (const float*)d_in[5];
    const float* pb2 = (const float*)d_in[6];
    const float* mw1 = (const float*)d_in[7];
    const float* mb1 = (const float*)d_in[8];
    const float* mw2 = (const float*)d_in[9];
    const float* mb2 = (const float*)d_in[10];
    const float* uw1 = (const float*)d_in[11];
    const float* ub1 = (const float*)d_in[12];
    const float* uw2 = (const float*)d_in[13];
    const float* ub2 = (const float*)d_in[14];
    float* out = (float*)d_out;

    char* ws = (char*)d_ws;
    float*          agg    = (float*)(ws);                      // 25,600,000 B
    unsigned short* xa     = (unsigned short*)(ws + 25600000);  // 12,800,000 B
    unsigned short* xb     = (unsigned short*)(ws + 38400000);  // 12,800,000 B
    float*          Wpc    = (float*)(ws + 51200000);           // 16,384 B
    float*          bcv    = (float*)(ws + 51216384);           // 512 B
    int*            flag   = (int*)(ws + 51216896);             // 256 B
    int*            cnt    = (int*)(ws + 51217152);             // 200,704 B
    int*            cursor = (int*)(ws + 51417856);             // 200,704 B
    int*            bsum   = (int*)(ws + 51618560);             // 256 B
    int2*           sRC    = (int2*)(ws + 51618816);            // 6,400,000 B

    unsigned short* tbuf = xa;  // xa dead after edge_kernel

    hipMemsetAsync(agg, 0, (size_t)NN * HD * sizeof(float), stream);
    hipMemsetAsync(cnt, 0, SCAN_BLOCKS * SCAN_CHUNK * sizeof(int), stream);
    prep_kernel<<<1, 256, 0, stream>>>(pw2, pb2, mw1, mb1, ei, Wpc, bcv, flag);
    hist_kernel<<<NE / 256, 256, 0, stream>>>(ei, flag, cnt);
    scan1_kernel<<<SCAN_BLOCKS, 256, 0, stream>>>(cnt, cursor, bsum);
    scan2_kernel<<<1, 64, 0, stream>>>(bsum);
    scan3_kernel<<<SCAN_BLOCKS, 256, 0, stream>>>(cursor, bsum);
    scatter_kernel<<<NE / 256, 256, 0, stream>>>(ei, flag, cursor, sRC);
    node_pre_kernel<<<512, 256, 0, stream>>>(x, mw1, xa, xb);
    edge_kernel<<<768, 256, 0, stream>>>(pos, sRC, pw1, pb1, mw2, mb2, xa, xb, Wpc, bcv, agg);
    upd1_kernel<<<512, 256, 0, stream>>>(x, agg, uw1, ub1, tbuf);
    upd2_kernel<<<768, 256, 0, stream>>>(tbuf, uw2, ub2, out);
}